// Round 12
// baseline (437.449 us; speedup 1.0000x reference)
//
#include <hip/hip_runtime.h>
#include <hip/hip_fp16.h>

#define NBINS 32
#define DIM 64
#define RANGE_MIN_F (-5.0f)
#define RANGE_MAX_F (5.0f)
#define NCELL 64
#define LUT_STRIDE 68            // (17d + g/4) % 32 spreads LUT rows across banks
#define BLOCK 512
#define GRID 1024                // persistent: 4 blocks/CU on 256 CUs
#define INV_CW 6.4f              // NCELL / (RANGE_MAX - RANGE_MIN)
#define GBIAS 32.0f              // -RANGE_MIN * INV_CW

typedef float f32x4 __attribute__((ext_vector_type(4)));   // native vector: OK for
                                                           // __builtin_nontemporal_*

// LDS budget per block (static):
//   s_rec DIM*NBINS*16 = 32768 B  {xk f32, yk f32, f16x2(iw,dk), f16x2(h,dk1)}
//   s_lut DIM*68       =  4352 B
//   total 37120 B -> 4 blocks/CU = 148.5 KB of 160 KB.
//
// R11 post-mortem: packed-record kernel measured ~102 us (434 dur - 2x166 us
// harness fills), 83% of the 85 us copy-roofline; f16 packing verified
// (absmax 0.03125 unchanged).  Remaining theory: imperfect HBM/LDS/VALU
// overlap from TLP shortfall at 24 waves/CU (VGPR-capped).  This round:
// __launch_bounds__(512,8) caps VGPR at 64 -> 32 waves/CU, GRID 768->1024
// so 4 blocks fit per CU.  Single delta vs R11.

__global__ __launch_bounds__(BLOCK, 8) void rqs_fused(
        const float* __restrict__ x,
        const float* __restrict__ bw,
        const float* __restrict__ bh,
        const float* __restrict__ ks,
        float* __restrict__ out,
        int total) {
    __shared__ float4 s_rec[DIM * NBINS];
    __shared__ unsigned char s_lut[DIM * LUT_STRIDE];

    const int t = threadIdx.x;

    // ---- phase 1: build records (2 groups of 64 threads, disjoint components) ----
    if (t < DIM) {
        // widths + left slopes: .x = xk, .z = pack(1/w, dk)
        const int d = t, sw = d >> 2;
        float acc = 0.0f;
        #pragma unroll
        for (int k = 0; k < NBINS; ++k) {
            float w  = bw[d * NBINS + k];
            float dk = (k == 0) ? 1.0f : ks[d * (NBINS - 1) + (k - 1)];
            int s = d * NBINS + ((k + sw) & (NBINS - 1));
            s_rec[s].x = RANGE_MIN_F + acc;
            __half2 hz = __floats2half2_rn(__builtin_amdgcn_rcpf(w), dk);
            s_rec[s].z = __builtin_bit_cast(float, hz);
            acc += w;
        }
    } else if (t < 2 * DIM) {
        // heights + right slopes: .y = yk, .w = pack(h, dk1)
        const int d = t - DIM, sw = d >> 2;
        float acc = 0.0f;
        #pragma unroll
        for (int k = 0; k < NBINS; ++k) {
            float h   = bh[d * NBINS + k];
            float dk1 = (k == NBINS - 1) ? 1.0f : ks[d * (NBINS - 1) + k];
            int s = d * NBINS + ((k + sw) & (NBINS - 1));
            s_rec[s].y = RANGE_MIN_F + acc;
            __half2 hw = __floats2half2_rn(h, dk1);
            s_rec[s].w = __builtin_bit_cast(float, hw);
            acc += h;
        }
    }
    __syncthreads();

    // ---- phase 2: LUT: lut[d][g] = max{p in [0,31] : kx[p] <= cellLeft(g)} ----
    const float cellw = (RANGE_MAX_F - RANGE_MIN_F) / (float)NCELL;
    #pragma unroll
    for (int e = 0; e < (DIM * NCELL + BLOCK - 1) / BLOCK; ++e) {
        int j = t + e * BLOCK;
        if (j < DIM * NCELL) {
            int d = j >> 6, g = j & (NCELL - 1);
            int sw = d >> 2;
            float cl = RANGE_MIN_F + (float)g * cellw;
            int p = 0;
            #pragma unroll
            for (int s = 16; s >= 1; s >>= 1) {
                float kxs = s_rec[d * NBINS + ((p + s + sw) & (NBINS - 1))].x;
                p += (kxs <= cl) ? s : 0;
            }
            s_lut[d * LUT_STRIDE + g] = (unsigned char)p;
        }
    }
    __syncthreads();

    // ---- per-element evaluator: LUT byte -> 2 PARALLEL b128 -> packed select ----
    auto eval1 = [&](float xv, int d) -> float {
        const int sw = d >> 2;
        float gf = fmaf(xv, INV_CW, GBIAS);
        gf = fminf(fmaxf(gf, 0.0f), (float)(NCELL - 1));   // v_med3
        int g = (int)gf;
        int p = (int)s_lut[d * LUT_STRIDE + g];
        int ix1 = d * NBINS + ((p + sw) & (NBINS - 1));
        int ix2 = d * NBINS + ((p + 1 + sw) & (NBINS - 1)); // wraps at p==31; dead then
        float4 r1 = s_rec[ix1];                             // independent: both issue
        float4 r2 = s_rec[ix2];                             // before one lgkmcnt wait
        bool adv = (xv >= r2.x) && (p < NBINS - 1);         // t1>=1 <=> xv >= xk[p+1]
        int sel = p + (adv ? 1 : 0);
        float xk = adv ? r2.x : r1.x;
        float yk = adv ? r2.y : r1.y;
        float pz = adv ? r2.z : r1.z;                       // select packed words,
        float pw = adv ? r2.w : r1.w;                       // convert once
        __half2 hz = __builtin_bit_cast(__half2, pz);
        __half2 hw = __builtin_bit_cast(__half2, pw);
        float iw  = __low2float(hz),  dk  = __high2float(hz);
        float h   = __low2float(hw),  dk1 = __high2float(hw);
        float tt0 = (xv - xk) * iw;
        // safety fixup for pathological >2-knot cells (~never taken)
        while (__builtin_expect((tt0 >= 1.0f) && (sel < NBINS - 1), 0)) {
            ++sel;
            float4 rr = s_rec[d * NBINS + ((sel + sw) & (NBINS - 1))];
            xk = rr.x; yk = rr.y;
            __half2 a = __builtin_bit_cast(__half2, rr.z);
            __half2 b = __builtin_bit_cast(__half2, rr.w);
            iw = __low2float(a); dk = __high2float(a);
            h  = __low2float(b); dk1 = __high2float(b);
            tt0 = (xv - xk) * iw;
        }
        float sm  = h * iw;                                 // bin mean slope s = h/w
        float tt  = tt0 * (1.0f - tt0);
        float num = h * fmaf(dk, tt, sm * tt0 * tt0);
        float den = fmaf(fmaf(-2.0f, sm, dk + dk1), tt, sm);
        float y   = fmaf(num, __builtin_amdgcn_rcpf(den), yk);
        bool inside = (xv >= RANGE_MIN_F) && (tt0 <= 1.0f);
        return inside ? y : xv;
    };

    // ---- phase 3: float4 streaming, persistent grid-stride, prefetch 1 deep ----
    const int tid  = blockIdx.x * BLOCK + t;
    const int TOTV = GRID * BLOCK;                 // float4 stride; 4*TOTV % 64 == 0
    const int d0   = (4 * tid) & (DIM - 1);        // dim of lane's first sub-element
    const int nvec = total >> 2;
    const f32x4* X4 = (const f32x4*)x;
    f32x4* O4 = (f32x4*)out;

    int v = tid;
    if (v < nvec) {
        f32x4 cur = __builtin_nontemporal_load(&X4[v]);
        while (true) {
            int vn = v + TOTV;
            bool more = (vn < nvec);
            f32x4 nxt = cur;
            if (more) nxt = __builtin_nontemporal_load(&X4[vn]);  // in flight during compute
            f32x4 r;
            r[0] = eval1(cur[0], d0 + 0);
            r[1] = eval1(cur[1], d0 + 1);
            r[2] = eval1(cur[2], d0 + 2);
            r[3] = eval1(cur[3], d0 + 3);
            __builtin_nontemporal_store(r, &O4[v]);
            if (!more) break;
            cur = nxt; v = vn;
        }
    }
    // tail (total % 4 != 0 safety; zero iterations for this problem size)
    int rem = total & 3;
    if (rem && tid < rem) {
        int i = (total & ~3) + tid;
        out[i] = eval1(x[i], i & (DIM - 1));
    }
}

extern "C" void kernel_launch(void* const* d_in, const int* in_sizes, int n_in,
                              void* d_out, int out_size, void* d_ws, size_t ws_size,
                              hipStream_t stream) {
    const float* x  = (const float*)d_in[0];
    const float* bw = (const float*)d_in[1];
    const float* bh = (const float*)d_in[2];
    const float* ks = (const float*)d_in[3];
    float* out = (float*)d_out;

    rqs_fused<<<GRID, BLOCK, 0, stream>>>(x, bw, bh, ks, out, out_size);
}